// Round 1
// baseline (149.795 us; speedup 1.0000x reference)
//
#include <hip/hip_runtime.h>

// Problem constants
constexpr int Bn = 16;
constexpr int Sn = 8192;
constexpr int Dn = 256;          // D_MODEL = K_CH = OUT = 256
constexpr float kScale = 0.0625f; // 1/sqrt(256)

// Workspace layout (float offsets)
constexpr int Q_OFF    = 0;                  // q[B][D]
constexpr int R_OFF    = Q_OFF + Bn * Dn;    // r[B][D]  (Wk @ q)
constexpr int C_OFF    = R_OFF + Bn * Dn;    // c[B]     (q . bk)
constexpr int SMAX_OFF = C_OFF + Bn;         // softmax max[B]
constexpr int SSUM_OFF = SMAX_OFF + Bn;      // 1/sum[B]
constexpr int CTX_OFF  = 8448;               // ctx[B][D]
constexpr int SC_OFF   = 16384;              // scores[B][S]
constexpr int NCHUNK   = 64;                 // s-chunks per batch for value pass
constexpr int PART_OFF = SC_OFF + Bn * Sn;   // partials[B][NCHUNK][D]
// total ws use: 409600 floats = 1.6 MB

// ---------------------------------------------------------------------------
// K1: per-batch tiny GEMVs: q = query@Wq + bq ; r = Wk@q ; c = q.bk
// grid = B blocks of 256 threads
__global__ __launch_bounds__(256) void k_qrc(
    const float* __restrict__ query, const float* __restrict__ Wq,
    const float* __restrict__ bq, const float* __restrict__ Wk,
    const float* __restrict__ bk, float* __restrict__ ws) {
  int b = blockIdx.x, i = threadIdx.x;
  __shared__ float qs[Dn];   // input query row
  __shared__ float qh[Dn];   // projected q
  __shared__ float red[256];
  qs[i] = query[b * Dn + i];
  __syncthreads();
  float acc = bq[i];
  #pragma unroll 8
  for (int d = 0; d < Dn; ++d) acc += qs[d] * Wq[d * Dn + i];  // coalesced over i
  qh[i] = acc;
  ws[Q_OFF + b * Dn + i] = acc;
  __syncthreads();
  // r[c] = sum_o Wk[c][o] * q[o]   (row read per thread; tiny, L2-cached)
  float racc = 0.f;
  #pragma unroll 8
  for (int o = 0; o < Dn; ++o) racc += Wk[i * Dn + o] * qh[o];
  ws[R_OFF + b * Dn + i] = racc;
  // c = q . bk
  red[i] = qh[i] * bk[i];
  __syncthreads();
  for (int off = 128; off; off >>= 1) {
    if (i < off) red[i] += red[i + off];
    __syncthreads();
  }
  if (i == 0) ws[C_OFF + b] = red[0];
}

// ---------------------------------------------------------------------------
// K2: scores[b][s] = (key[b,s,:].r[b] + c[b]) * scale
// One wave per score row iteration; each block (4 waves) does 32 rows.
// grid = B * S / 32 = 4096
__global__ __launch_bounds__(256) void k_scores(
    const float* __restrict__ key, float* __restrict__ ws) {
  int blk = blockIdx.x;
  int b = blk >> 8;               // 256 blocks per batch
  int s0 = (blk & 255) * 32;
  int t = threadIdx.x, lane = t & 63, wv = t >> 6;
  float4 rv = ((const float4*)(ws + R_OFF + b * Dn))[lane];  // reused 8x
  float cb = ws[C_OFF + b];
  const float4* kp = (const float4*)(key + ((size_t)b * Sn + s0) * Dn);
  #pragma unroll
  for (int it = 0; it < 8; ++it) {
    int sl = wv + 4 * it;
    float4 kv = kp[(size_t)sl * 64 + lane];  // 64 lanes x 16B = full 1KB row
    float dot = kv.x * rv.x + kv.y * rv.y + kv.z * rv.z + kv.w * rv.w;
    #pragma unroll
    for (int off = 32; off; off >>= 1) dot += __shfl_xor(dot, off, 64);
    if (lane == 0) ws[SC_OFF + b * Sn + s0 + sl] = (dot + cb) * kScale;
  }
}

// ---------------------------------------------------------------------------
// K3: per-batch softmax stats: max and 1/sum(exp)
// grid = B blocks of 256 threads (reads 32 KB/block from L2)
__global__ __launch_bounds__(256) void k_stats(float* __restrict__ ws) {
  int b = blockIdx.x, t = threadIdx.x;
  __shared__ float red[256];
  const float* sc = ws + SC_OFF + b * Sn;
  float m = -1e30f;
  for (int s = t; s < Sn; s += 256) m = fmaxf(m, sc[s]);
  red[t] = m;
  __syncthreads();
  for (int off = 128; off; off >>= 1) {
    if (t < off) red[t] = fmaxf(red[t], red[t + off]);
    __syncthreads();
  }
  float gm = red[0];
  __syncthreads();
  float sum = 0.f;
  for (int s = t; s < Sn; s += 256) sum += __expf(sc[s] - gm);
  red[t] = sum;
  __syncthreads();
  for (int off = 128; off; off >>= 1) {
    if (t < off) red[t] += red[t + off];
    __syncthreads();
  }
  if (t == 0) {
    ws[SMAX_OFF + b] = gm;
    ws[SSUM_OFF + b] = 1.0f / red[0];
  }
}

// ---------------------------------------------------------------------------
// K4: partial weighted value sums. Each block: one batch, one 128-row s-chunk.
// grid = B * NCHUNK = 1024 blocks of 256 threads (4 waves, float4 per lane)
__global__ __launch_bounds__(256) void k_vpart(
    const float* __restrict__ value, float* __restrict__ ws) {
  int blk = blockIdx.x;
  int b = blk >> 6;       // / NCHUNK
  int chunk = blk & 63;
  int s0 = chunk * (Sn / NCHUNK);  // 128 rows
  int t = threadIdx.x, lane = t & 63, wv = t >> 6;
  __shared__ float wsh[Sn / NCHUNK];  // 128 softmax weights
  __shared__ float red[4][Dn];
  float gm = ws[SMAX_OFF + b], sinv = ws[SSUM_OFF + b];
  if (t < Sn / NCHUNK)
    wsh[t] = __expf(ws[SC_OFF + b * Sn + s0 + t] - gm) * sinv;
  __syncthreads();
  float4 acc = {0.f, 0.f, 0.f, 0.f};
  const float4* vp = (const float4*)(value + ((size_t)b * Sn + s0) * Dn);
  #pragma unroll 4
  for (int it = 0; it < 32; ++it) {
    int sl = wv + 4 * it;
    float4 v = vp[(size_t)sl * 64 + lane];
    float w = wsh[sl];
    acc.x += w * v.x; acc.y += w * v.y; acc.z += w * v.z; acc.w += w * v.w;
  }
  red[wv][lane * 4 + 0] = acc.x;
  red[wv][lane * 4 + 1] = acc.y;
  red[wv][lane * 4 + 2] = acc.z;
  red[wv][lane * 4 + 3] = acc.w;
  __syncthreads();
  float sum = red[0][t] + red[1][t] + red[2][t] + red[3][t];
  ws[PART_OFF + (b * NCHUNK + chunk) * Dn + t] = sum;
}

// ---------------------------------------------------------------------------
// K5: reduce partials -> u[b][:], then ctx = u@Wv + bv
// grid = B blocks of 256 threads
__global__ __launch_bounds__(256) void k_ctx(
    const float* __restrict__ Wv, const float* __restrict__ bv,
    float* __restrict__ ws) {
  int b = blockIdx.x, t = threadIdx.x;
  __shared__ float ush[Dn];
  float u = 0.f;
  #pragma unroll 8
  for (int ch = 0; ch < NCHUNK; ++ch)
    u += ws[PART_OFF + (b * NCHUNK + ch) * Dn + t];
  ush[t] = u;
  __syncthreads();
  float acc = bv[t];
  #pragma unroll 8
  for (int o = 0; o < Dn; ++o) acc += ush[o] * Wv[o * Dn + t];  // coalesced over t
  ws[CTX_OFF + b * Dn + t] = acc;
}

// ---------------------------------------------------------------------------
// K6: broadcast ctx[b][:] to out[b][s][:] for all s. Pure 128 MiB write.
// grid = B * 128 blocks; each block writes 64 s-rows (64 KiB)
__global__ __launch_bounds__(256) void k_bcast(
    const float* __restrict__ ws, float* __restrict__ out) {
  int b = blockIdx.x >> 7;
  int sb = blockIdx.x & 127;
  int t = threadIdx.x, lane = t & 63, wv = t >> 6;
  float4 val = ((const float4*)(ws + CTX_OFF + b * Dn))[lane];  // load once
  float4* op = (float4*)(out + ((size_t)b * Sn + sb * 64) * Dn);
  #pragma unroll
  for (int it = 0; it < 16; ++it) {
    int sl = wv + 4 * it;
    op[(size_t)sl * 64 + lane] = val;
  }
}

// ---------------------------------------------------------------------------
extern "C" void kernel_launch(void* const* d_in, const int* in_sizes, int n_in,
                              void* d_out, int out_size, void* d_ws, size_t ws_size,
                              hipStream_t stream) {
  const float* query = (const float*)d_in[0];
  const float* key   = (const float*)d_in[1];
  const float* value = (const float*)d_in[2];
  const float* Wq    = (const float*)d_in[3];
  const float* bq    = (const float*)d_in[4];
  const float* Wk    = (const float*)d_in[5];
  const float* bk    = (const float*)d_in[6];
  const float* Wv    = (const float*)d_in[7];
  const float* bv    = (const float*)d_in[8];
  float* out = (float*)d_out;
  float* ws  = (float*)d_ws;

  hipLaunchKernelGGL(k_qrc,    dim3(Bn),        dim3(256), 0, stream,
                     query, Wq, bq, Wk, bk, ws);
  hipLaunchKernelGGL(k_scores, dim3(4096),      dim3(256), 0, stream, key, ws);
  hipLaunchKernelGGL(k_stats,  dim3(Bn),        dim3(256), 0, stream, ws);
  hipLaunchKernelGGL(k_vpart,  dim3(Bn * 64),   dim3(256), 0, stream, value, ws);
  hipLaunchKernelGGL(k_ctx,    dim3(Bn),        dim3(256), 0, stream, Wv, bv, ws);
  hipLaunchKernelGGL(k_bcast,  dim3(Bn * 128),  dim3(256), 0, stream, ws, out);
}

// Round 3
// 106.752 us; speedup vs baseline: 1.4032x; 1.4032x over previous
//
#include <hip/hip_runtime.h>

typedef float f4 __attribute__((ext_vector_type(4)));  // native vector for nt ld/st

// Problem constants
constexpr int Bn = 16;
constexpr int Sn = 8192;
constexpr int Dn = 256;           // D_MODEL = K_CH = OUT = 256
constexpr float kScale = 0.0625f; // 1/sqrt(256)
constexpr int NCHUNK = 64;        // s-chunks per batch
constexpr int CHUNK  = Sn / NCHUNK; // 128 rows per chunk

// Workspace layout (float offsets); total ~272k floats = 1.09 MB
constexpr int R_OFF    = 0;                     // r[B][D] = Wk @ q
constexpr int C_OFF    = R_OFF + Bn * Dn;       // c[B]    = q . bk
constexpr int CTX_OFF  = C_OFF + 64;            // ctx[B][D]
constexpr int M_OFF    = CTX_OFF + Bn * Dn;     // chunk max  [B][NCHUNK]
constexpr int SUM_OFF  = M_OFF + Bn * NCHUNK;   // chunk expsum[B][NCHUNK]
constexpr int PART_OFF = SUM_OFF + Bn * NCHUNK; // partials [B][NCHUNK][D]

// ---------------------------------------------------------------------------
// K1: per-batch tiny GEMVs: q = query@Wq + bq ; r = Wk@q ; c = q.bk
__global__ __launch_bounds__(256) void k_qrc(
    const float* __restrict__ query, const float* __restrict__ Wq,
    const float* __restrict__ bq, const float* __restrict__ Wk,
    const float* __restrict__ bk, float* __restrict__ ws) {
  int b = blockIdx.x, i = threadIdx.x;
  __shared__ float qs[Dn];
  __shared__ float qh[Dn];
  __shared__ float red[256];
  qs[i] = query[b * Dn + i];
  __syncthreads();
  float acc = bq[i];
  #pragma unroll 8
  for (int d = 0; d < Dn; ++d) acc += qs[d] * Wq[d * Dn + i];  // coalesced over i
  qh[i] = acc;
  __syncthreads();
  float racc = 0.f;
  #pragma unroll 8
  for (int o = 0; o < Dn; ++o) racc += Wk[i * Dn + o] * qh[o];
  ws[R_OFF + b * Dn + i] = racc;
  red[i] = qh[i] * bk[i];
  __syncthreads();
  for (int off = 128; off; off >>= 1) {
    if (i < off) red[i] += red[i + off];
    __syncthreads();
  }
  if (i == 0) ws[C_OFF + b] = red[0];
}

// ---------------------------------------------------------------------------
// K2 (fused): per (batch, chunk): scores -> local softmax -> weighted V partial.
// Reads key chunk (128 KiB) + value chunk (128 KiB) exactly once each.
// grid = B * NCHUNK = 1024 blocks, 256 threads (4 waves)
__global__ __launch_bounds__(256) void k_fused(
    const float* __restrict__ key, const float* __restrict__ value,
    float* __restrict__ ws) {
  int blk = blockIdx.x;
  int b = blk >> 6;        // / NCHUNK
  int chunk = blk & 63;
  int s0 = chunk * CHUNK;
  int t = threadIdx.x, lane = t & 63, wv = t >> 6;
  __shared__ float sc[CHUNK];   // raw scores
  __shared__ float wsh[CHUNK];  // exp(s - m_c)
  __shared__ float red[4][Dn];

  f4 rv = ((const f4*)(ws + R_OFF + b * Dn))[lane];
  float cb = ws[C_OFF + b];
  const f4* kp = (const f4*)(key + ((size_t)b * Sn + s0) * Dn);
  const f4* vp = (const f4*)(value + ((size_t)b * Sn + s0) * Dn);

  // Phase 1: scores for 128 rows (each wave: 32 rows, 1 KiB coalesced per row)
  #pragma unroll 4
  for (int i = 0; i < CHUNK / 4; ++i) {
    int sl = wv + 4 * i;
    f4 kv = __builtin_nontemporal_load(&kp[(size_t)sl * 64 + lane]);
    float dot = kv.x * rv.x + kv.y * rv.y + kv.z * rv.z + kv.w * rv.w;
    #pragma unroll
    for (int off = 32; off; off >>= 1) dot += __shfl_xor(dot, off, 64);
    if (lane == 0) sc[sl] = (dot + cb) * kScale;
  }
  __syncthreads();

  // Chunk-local max (uniform broadcast reads, no divergence)
  float m = -1e30f;
  #pragma unroll 8
  for (int i = 0; i < CHUNK; ++i) m = fmaxf(m, sc[i]);
  if (t < CHUNK) wsh[t] = __expf(sc[t] - m);
  __syncthreads();

  // Phase 2: weighted value partial
  f4 acc = {0.f, 0.f, 0.f, 0.f};
  #pragma unroll 4
  for (int i = 0; i < CHUNK / 4; ++i) {
    int sl = wv + 4 * i;
    f4 v = __builtin_nontemporal_load(&vp[(size_t)sl * 64 + lane]);
    float w = wsh[sl];
    acc.x += w * v.x; acc.y += w * v.y; acc.z += w * v.z; acc.w += w * v.w;
  }
  red[wv][lane * 4 + 0] = acc.x;
  red[wv][lane * 4 + 1] = acc.y;
  red[wv][lane * 4 + 2] = acc.z;
  red[wv][lane * 4 + 3] = acc.w;
  __syncthreads();
  float part = red[0][t] + red[1][t] + red[2][t] + red[3][t];
  ws[PART_OFF + ((size_t)b * NCHUNK + chunk) * Dn + t] = part;
  if (t == 0) {
    float ssum = 0.f;
    #pragma unroll 8
    for (int i = 0; i < CHUNK; ++i) ssum += wsh[i];
    ws[M_OFF + b * NCHUNK + chunk] = m;
    ws[SUM_OFF + b * NCHUNK + chunk] = ssum;
  }
}

// ---------------------------------------------------------------------------
// K3: combine chunk partials (log-sum-exp rescale) -> u; ctx = (u/denom)@Wv + bv
// grid = B blocks of 256 threads
__global__ __launch_bounds__(256) void k_combine(
    const float* __restrict__ Wv, const float* __restrict__ bv,
    float* __restrict__ ws) {
  int b = blockIdx.x, t = threadIdx.x;
  __shared__ float msh[NCHUNK];
  __shared__ float e[NCHUNK];
  __shared__ float ush[Dn];
  if (t < NCHUNK) msh[t] = ws[M_OFF + b * NCHUNK + t];
  __syncthreads();
  float gm = -1e30f;
  #pragma unroll 8
  for (int c = 0; c < NCHUNK; ++c) gm = fmaxf(gm, msh[c]);
  if (t < NCHUNK) e[t] = __expf(msh[t] - gm);
  __syncthreads();
  float denom = 0.f;
  #pragma unroll 8
  for (int c = 0; c < NCHUNK; ++c) denom += ws[SUM_OFF + b * NCHUNK + c] * e[c];
  float u = 0.f;
  #pragma unroll 8
  for (int c = 0; c < NCHUNK; ++c)
    u += ws[PART_OFF + ((size_t)b * NCHUNK + c) * Dn + t] * e[c];  // coalesced over t
  ush[t] = u / denom;
  __syncthreads();
  float acc = bv[t];
  #pragma unroll 8
  for (int o = 0; o < Dn; ++o) acc += ush[o] * Wv[o * Dn + t];  // coalesced over t
  ws[CTX_OFF + b * Dn + t] = acc;
}

// ---------------------------------------------------------------------------
// K4: broadcast ctx[b][:] to out[b][s][:]. Pure 128 MiB streaming write.
// grid = B * 128 blocks; each block writes 64 s-rows (64 KiB), nontemporal
__global__ __launch_bounds__(256) void k_bcast(
    const float* __restrict__ ws, float* __restrict__ out) {
  int b = blockIdx.x >> 7;
  int sb = blockIdx.x & 127;
  int t = threadIdx.x, lane = t & 63, wv = t >> 6;
  f4 val = ((const f4*)(ws + CTX_OFF + b * Dn))[lane];
  f4* op = (f4*)(out + ((size_t)b * Sn + sb * 64) * Dn);
  #pragma unroll
  for (int it = 0; it < 16; ++it) {
    int sl = wv + 4 * it;
    __builtin_nontemporal_store(val, &op[(size_t)sl * 64 + lane]);
  }
}

// ---------------------------------------------------------------------------
extern "C" void kernel_launch(void* const* d_in, const int* in_sizes, int n_in,
                              void* d_out, int out_size, void* d_ws, size_t ws_size,
                              hipStream_t stream) {
  const float* query = (const float*)d_in[0];
  const float* key   = (const float*)d_in[1];
  const float* value = (const float*)d_in[2];
  const float* Wq    = (const float*)d_in[3];
  const float* bq    = (const float*)d_in[4];
  const float* Wk    = (const float*)d_in[5];
  const float* bk    = (const float*)d_in[6];
  const float* Wv    = (const float*)d_in[7];
  const float* bv    = (const float*)d_in[8];
  float* out = (float*)d_out;
  float* ws  = (float*)d_ws;

  hipLaunchKernelGGL(k_qrc,     dim3(Bn),          dim3(256), 0, stream,
                     query, Wq, bq, Wk, bk, ws);
  hipLaunchKernelGGL(k_fused,   dim3(Bn * NCHUNK), dim3(256), 0, stream,
                     key, value, ws);
  hipLaunchKernelGGL(k_combine, dim3(Bn),          dim3(256), 0, stream,
                     Wv, bv, ws);
  hipLaunchKernelGGL(k_bcast,   dim3(Bn * 128),    dim3(256), 0, stream, ws, out);
}